// Round 1
// baseline (8527.039 us; speedup 1.0000x reference)
//
#include <hip/hip_runtime.h>
#include <math.h>

// Problem constants (fixed by setup_inputs).
constexpr int B     = 2048;
constexpr int D     = 512;
constexpr int N     = 100000;
constexpr int KTOP  = 5;
constexpr int NPART = 16;              // N split across 16 column-parts
constexpr int CHUNK = N / NPART;       // 6250 exactly
constexpr int BM    = 64;              // queries per block
constexpr int BN    = 64;              // points per subtile
constexpr int BK    = 32;              // k-tile
constexpr int LSTR  = BK + 4;          // 36: float4-aligned, bank-friendly

// ---------------- x2 = ||x||^2 per point: one wave per row ----------------
__global__ void x2_kernel(const float* __restrict__ X, float* __restrict__ x2) {
    int lane = threadIdx.x & 63;
    int wid  = (int)((blockIdx.x * blockDim.x + threadIdx.x) >> 6);
    if (wid >= N) return;
    const float* row = X + (size_t)wid * D;
    float s = 0.f;
    for (int c = lane; c < D; c += 64) { float v = row[c]; s = fmaf(v, v, s); }
#pragma unroll
    for (int off = 32; off > 0; off >>= 1) s += __shfl_down(s, off);
    if (lane == 0) x2[wid] = s;
}

// ---------------- main: scores + per-part top-5 ----------------
union SMem {
    struct {
        float Qs[BM][LSTR];
        float Xs[BN][LSTR];
        float x2s[BN];
    } tile;
    struct {
        float ms[BM * 16 * KTOP];
        int   mi[BM * 16 * KTOP];
    } merge;
};

__launch_bounds__(256)
__global__ void knn_main(const float* __restrict__ Q, const float* __restrict__ X,
                         const float* __restrict__ x2g,
                         float* __restrict__ cand_s, int* __restrict__ cand_i) {
    __shared__ SMem sm;
    const int t  = threadIdx.x;
    const int tx = t & 15;    // column group: cols tx + 16j
    const int ty = t >> 4;    // row group:    rows ty + 16i
    const int qbase  = blockIdx.x * BM;
    const int part   = blockIdx.y;
    const int pstart = part * CHUNK;
    const int pend   = pstart + CHUNK;

    // Per-thread running top-5, sorted descending (ts[.][0] best).
    float ts[4][KTOP];
    int   ti[4][KTOP];
#pragma unroll
    for (int i = 0; i < 4; ++i)
#pragma unroll
        for (int k = 0; k < KTOP; ++k) { ts[i][k] = -INFINITY; ti[i][k] = 0x7fffffff; }

    for (int sb = pstart; sb < pend; sb += BN) {
        __syncthreads();   // previous subtile's x2s readers done
        if (t < BN) {
            int p = sb + t;
            sm.tile.x2s[t] = (p < pend) ? x2g[p] : INFINITY;  // INF masks OOB cols
        }
        float acc[4][4];
#pragma unroll
        for (int i = 0; i < 4; ++i)
#pragma unroll
            for (int j = 0; j < 4; ++j) acc[i][j] = 0.f;

        for (int k0 = 0; k0 < D; k0 += BK) {
            __syncthreads();   // previous k-step's tile readers done
            // Stage Q and X tiles: 2 float4 each per thread, coalesced (8 lanes/row).
#pragma unroll
            for (int u = 0; u < 2; ++u) {
                int f   = t + u * 256;           // 0..511
                int row = f >> 3;
                int cf  = (f & 7) * 4;
                *(float4*)&sm.tile.Qs[row][cf] =
                    *(const float4*)&Q[(size_t)(qbase + row) * D + k0 + cf];
                int prow = sb + row;
                if (prow > N - 1) prow = N - 1;  // clamp; masked via x2s=INF
                *(float4*)&sm.tile.Xs[row][cf] =
                    *(const float4*)&X[(size_t)prow * D + k0 + cf];
            }
            __syncthreads();
#pragma unroll
            for (int kk = 0; kk < BK; kk += 4) {
                float4 qv[4], xv[4];
#pragma unroll
                for (int i = 0; i < 4; ++i) qv[i] = *(const float4*)&sm.tile.Qs[ty + 16 * i][kk];
#pragma unroll
                for (int j = 0; j < 4; ++j) xv[j] = *(const float4*)&sm.tile.Xs[tx + 16 * j][kk];
#pragma unroll
                for (int i = 0; i < 4; ++i)
#pragma unroll
                    for (int j = 0; j < 4; ++j) {
                        acc[i][j] = fmaf(qv[i].x, xv[j].x, acc[i][j]);
                        acc[i][j] = fmaf(qv[i].y, xv[j].y, acc[i][j]);
                        acc[i][j] = fmaf(qv[i].z, xv[j].z, acc[i][j]);
                        acc[i][j] = fmaf(qv[i].w, xv[j].w, acc[i][j]);
                    }
            }
        }
        // Scores + top-5 insertion (common case: 1 compare, fails).
#pragma unroll
        for (int j = 0; j < 4; ++j) {
            int   p  = sb + tx + 16 * j;
            float xx = sm.tile.x2s[tx + 16 * j];
#pragma unroll
            for (int i = 0; i < 4; ++i) {
                float s = 2.f * acc[i][j] - xx;
                if (s > ts[i][KTOP - 1]) {       // strict >: ties keep earlier idx
                    ts[i][KTOP - 1] = s; ti[i][KTOP - 1] = p;
#pragma unroll
                    for (int k = KTOP - 1; k > 0; --k) {
                        if (ts[i][k] > ts[i][k - 1]) {
                            float tf = ts[i][k]; ts[i][k] = ts[i][k - 1]; ts[i][k - 1] = tf;
                            int   tg = ti[i][k]; ti[i][k] = ti[i][k - 1]; ti[i][k - 1] = tg;
                        }
                    }
                }
            }
        }
    }

    __syncthreads();   // done with tile union member
#pragma unroll
    for (int i = 0; i < 4; ++i) {
        int row = ty + 16 * i;
        for (int k = 0; k < KTOP; ++k) {
            sm.merge.ms[row * 80 + tx * KTOP + k] = ts[i][k];
            sm.merge.mi[row * 80 + tx * KTOP + k] = ti[i][k];
        }
    }
    __syncthreads();
    if (t < BM) {
        float bs[KTOP]; int bi[KTOP];
#pragma unroll
        for (int k = 0; k < KTOP; ++k) { bs[k] = -INFINITY; bi[k] = 0x7fffffff; }
        for (int c = 0; c < 16 * KTOP; ++c) {
            float s = sm.merge.ms[t * 80 + c];
            int   p = sm.merge.mi[t * 80 + c];
            if (s > bs[KTOP - 1] || (s == bs[KTOP - 1] && p < bi[KTOP - 1])) {
                bs[KTOP - 1] = s; bi[KTOP - 1] = p;
#pragma unroll
                for (int k = KTOP - 1; k > 0; --k) {
                    bool up = (bs[k] > bs[k - 1]) || (bs[k] == bs[k - 1] && bi[k] < bi[k - 1]);
                    if (up) {
                        float tf = bs[k]; bs[k] = bs[k - 1]; bs[k - 1] = tf;
                        int   tg = bi[k]; bi[k] = bi[k - 1]; bi[k - 1] = tg;
                    }
                }
            }
        }
        int q = qbase + t;
        for (int k = 0; k < KTOP; ++k) {
            cand_s[(size_t)(q * NPART + part) * KTOP + k] = bs[k];
            cand_i[(size_t)(q * NPART + part) * KTOP + k] = bi[k];
        }
    }
}

// ---------------- final merge across parts + label vote ----------------
__global__ void vote_kernel(const float* __restrict__ cand_s, const int* __restrict__ cand_i,
                            const int* __restrict__ Y, float* __restrict__ out) {
    int q = blockIdx.x * blockDim.x + threadIdx.x;
    if (q >= B) return;
    float bs[KTOP]; int bi[KTOP];
#pragma unroll
    for (int k = 0; k < KTOP; ++k) { bs[k] = -INFINITY; bi[k] = 0x7fffffff; }
    for (int c = 0; c < NPART * KTOP; ++c) {
        float s = cand_s[(size_t)q * NPART * KTOP + c];
        int   p = cand_i[(size_t)q * NPART * KTOP + c];
        if (s > bs[KTOP - 1] || (s == bs[KTOP - 1] && p < bi[KTOP - 1])) {
            bs[KTOP - 1] = s; bi[KTOP - 1] = p;
#pragma unroll
            for (int k = KTOP - 1; k > 0; --k) {
                bool up = (bs[k] > bs[k - 1]) || (bs[k] == bs[k - 1] && bi[k] < bi[k - 1]);
                if (up) {
                    float tf = bs[k]; bs[k] = bs[k - 1]; bs[k - 1] = tf;
                    int   tg = bi[k]; bi[k] = bi[k - 1]; bi[k - 1] = tg;
                }
            }
        }
    }
    float sum = 0.f;
#pragma unroll
    for (int k = 0; k < KTOP; ++k) sum += (float)Y[bi[k]];
    out[2 * q]     = sum / (float)KTOP;
    out[2 * q + 1] = 0.f;
}

extern "C" void kernel_launch(void* const* d_in, const int* in_sizes, int n_in,
                              void* d_out, int out_size, void* d_ws, size_t ws_size,
                              hipStream_t stream) {
    const float* Q = (const float*)d_in[0];
    const float* X = (const float*)d_in[1];
    const int*   Y = (const int*)d_in[2];
    // d_in[3] is K==5, hardcoded.
    float* out = (float*)d_out;

    float* x2     = (float*)d_ws;                      // N floats
    float* cand_s = x2 + N;                            // B*NPART*KTOP floats
    int*   cand_i = (int*)(cand_s + (size_t)B * NPART * KTOP);

    hipLaunchKernelGGL(x2_kernel, dim3((N + 3) / 4), dim3(256), 0, stream, X, x2);
    hipLaunchKernelGGL(knn_main, dim3(B / BM, NPART), dim3(256), 0, stream,
                       Q, X, x2, cand_s, cand_i);
    hipLaunchKernelGGL(vote_kernel, dim3((B + 255) / 256), dim3(256), 0, stream,
                       cand_s, cand_i, Y, out);
}

// Round 2
// 1023.912 us; speedup vs baseline: 8.3279x; 8.3279x over previous
//
#include <hip/hip_runtime.h>
#include <math.h>

typedef unsigned int   u32;
typedef unsigned short u16;
typedef short short8 __attribute__((ext_vector_type(8)));   // 8 bf16 = 4 VGPRs
typedef float f32x4  __attribute__((ext_vector_type(4)));

constexpr int B     = 2048;
constexpr int D     = 512;
constexpr int N     = 100000;
constexpr int KTOP  = 5;
constexpr int NPART = 128;
constexpr int CHUNK = 782;            // ceil(N/NPART); last part has 686
constexpr int QBLK  = 256;            // queries per block in main kernel
constexpr int PSUB  = 64;             // points per subtile
constexpr int KTILE = 32;             // K per MFMA (16x16x32)
constexpr int NK    = D / KTILE;      // 16 k-steps

__device__ __forceinline__ u16 f2bf(float f) {   // RNE, inputs are finite normals
    u32 u = __float_as_uint(f);
    return (u16)((u + 0x7fffu + ((u >> 16) & 1u)) >> 16);
}

__device__ __forceinline__ void gld_lds16(const void* g, void* l) {
    __builtin_amdgcn_global_load_lds((const __attribute__((address_space(1))) u32*)g,
                                     (__attribute__((address_space(3))) u32*)l, 16, 0, 0);
}

// ---- Q -> bf16, pre-arranged in MFMA B-frag order -------------------------
// frag g = (q>>4)*NK + (k>>5); within frag: lane=(q&15)+16*((k>>3)&3), elem k&7
__global__ void prep_q(const float* __restrict__ Q, u16* __restrict__ Qbf) {
    int tid  = blockIdx.x * 256 + threadIdx.x;     // 131072 total
    int q    = tid >> 6;
    int koct = tid & 63;                           // k = koct*8
    const float4* src = (const float4*)(Q + (size_t)q * D + koct * 8);
    float4 a = src[0], b = src[1];
    u32 p0 = (u32)f2bf(a.x) | ((u32)f2bf(a.y) << 16);
    u32 p1 = (u32)f2bf(a.z) | ((u32)f2bf(a.w) << 16);
    u32 p2 = (u32)f2bf(b.x) | ((u32)f2bf(b.y) << 16);
    u32 p3 = (u32)f2bf(b.z) | ((u32)f2bf(b.w) << 16);
    int frag = (q >> 4) * NK + (koct >> 2);
    int lane = (q & 15) + 16 * (koct & 3);
    *(uint4*)(Qbf + (size_t)frag * 512 + lane * 8) = make_uint4(p0, p1, p2, p3);
}

// ---- x2 = ||x||^2 (exact fp32), one wave per row --------------------------
__global__ void x2_kernel(const float* __restrict__ X, float* __restrict__ x2) {
    int lane = threadIdx.x & 63;
    int wid  = (int)((blockIdx.x * blockDim.x + threadIdx.x) >> 6);
    if (wid >= N) return;
    const float* row = X + (size_t)wid * D;
    float s = 0.f;
    for (int c = lane; c < D; c += 64) { float v = row[c]; s = fmaf(v, v, s); }
#pragma unroll
    for (int off = 32; off > 0; off >>= 1) s += __shfl_down(s, off);
    if (lane == 0) x2[wid] = s;
}

// ---- merge two sorted-desc top-5 lists across xor-partner lanes -----------
__device__ __forceinline__ void merge_xor(float (&s)[KTOP], int (&x)[KTOP], int mask) {
    float bs[KTOP], as[KTOP]; int bx[KTOP], ax[KTOP];
#pragma unroll
    for (int k = 0; k < KTOP; ++k) {
        bs[k] = __shfl_xor(s[k], mask); bx[k] = __shfl_xor(x[k], mask);
        as[k] = s[k]; ax[k] = x[k];
    }
#pragma unroll
    for (int k = 0; k < KTOP; ++k) {
        bool ta = (as[0] > bs[0]) || ((as[0] == bs[0]) && (ax[0] < bx[0]));
        s[k] = ta ? as[0] : bs[0];
        x[k] = ta ? ax[0] : bx[0];
#pragma unroll
        for (int m = 0; m < KTOP - 1; ++m) {
            as[m] = ta ? as[m + 1] : as[m];  ax[m] = ta ? ax[m + 1] : ax[m];
            bs[m] = ta ? bs[m]     : bs[m + 1]; bx[m] = ta ? bx[m] : bx[m + 1];
        }
        as[KTOP - 1] = ta ? -INFINITY : as[KTOP - 1];
        bs[KTOP - 1] = ta ? bs[KTOP - 1] : -INFINITY;
    }
}

// ---- main: bf16 MFMA scores (C^T: rows=points, cols=queries) + top-5/part --
__launch_bounds__(256)
__global__ void knn_mfma(const float* __restrict__ X, const u16* __restrict__ Qbf,
                         const float* __restrict__ x2g,
                         float* __restrict__ cand_s, int* __restrict__ cand_i) {
    __shared__ __attribute__((aligned(16))) u16 Bfr[16 * 512];   // 16 Q-frags (256 q x 32 k)
    __shared__ __attribute__((aligned(16))) u16 Afr[4 * 512];    // 4 X-frags  (64 p x 32 k)
    __shared__ float x2s[PSUB];

    const int t    = threadIdx.x;
    const int lane = t & 63;
    const int wave = t >> 6;          // 0..3 = query 64-group, also A-frag id for staging
    const int quad = lane >> 4;
    const int col  = lane & 15;
    const int qb   = blockIdx.x;      // 0..7
    const int part = blockIdx.y;      // 0..127
    const int pstart = part * CHUNK;
    const int pend   = min(pstart + CHUNK, N);

    float ss[4][KTOP]; int si[4][KTOP];
#pragma unroll
    for (int j = 0; j < 4; ++j)
#pragma unroll
        for (int k = 0; k < KTOP; ++k) { ss[j][k] = -INFINITY; si[j][k] = 0x7fffffff; }

    const int nsub = (pend - pstart + PSUB - 1) / PSUB;
    for (int sbi = 0; sbi < nsub; ++sbi) {
        const int sb = pstart + sbi * PSUB;
        __syncthreads();                                   // prior subtile's x2s readers done
        if (t < PSUB) x2s[t] = (sb + t < pend) ? x2g[sb + t] : INFINITY;

        f32x4 acc[4][4];
#pragma unroll
        for (int i = 0; i < 4; ++i)
#pragma unroll
            for (int j = 0; j < 4; ++j) acc[i][j] = (f32x4)0.f;

        for (int k0i = 0; k0i < NK; ++k0i) {
            const int k0 = k0i * KTILE;
            __syncthreads();                               // prior iter's frag readers done
            {   // stage A-frag[wave]: convert 8 fp32 -> 8 bf16, lane-linear ds_write_b128
                int prow = sb + wave * 16 + col;
                if (prow >= pend) prow = pend - 1;         // clamp; masked via x2s=INF
                const float4* src = (const float4*)(X + (size_t)prow * D + k0 + quad * 8);
                float4 a = src[0], b = src[1];
                u32 p0 = (u32)f2bf(a.x) | ((u32)f2bf(a.y) << 16);
                u32 p1 = (u32)f2bf(a.z) | ((u32)f2bf(a.w) << 16);
                u32 p2 = (u32)f2bf(b.x) | ((u32)f2bf(b.y) << 16);
                u32 p3 = (u32)f2bf(b.z) | ((u32)f2bf(b.w) << 16);
                *(uint4*)(Afr + wave * 512 + lane * 8) = make_uint4(p0, p1, p2, p3);
            }
#pragma unroll
            for (int j = 0; j < 4; ++j) {                  // stage this wave's 4 B-frags
                int qgrp = qb * 16 + wave * 4 + j;
                const u16* src = Qbf + ((size_t)qgrp * NK + k0i) * 512 + lane * 8;
                gld_lds16(src, Bfr + (wave * 4 + j) * 512);
            }
            __syncthreads();                               // drains vmcnt (global_load_lds)
            short8 af[4], bf[4];
#pragma unroll
            for (int i = 0; i < 4; ++i) af[i] = *(const short8*)(Afr + i * 512 + lane * 8);
#pragma unroll
            for (int j = 0; j < 4; ++j) bf[j] = *(const short8*)(Bfr + (wave * 4 + j) * 512 + lane * 8);
#pragma unroll
            for (int i = 0; i < 4; ++i)
#pragma unroll
                for (int j = 0; j < 4; ++j)
                    acc[i][j] = __builtin_amdgcn_mfma_f32_16x16x32_bf16(af[i], bf[j], acc[i][j], 0, 0, 0);
        }

        // selection: score = 2*acc - x2 ; C layout: col=lane&15(query), row=quad*4+reg(point)
#pragma unroll
        for (int i = 0; i < 4; ++i) {
            int pbase = 16 * i + quad * 4;
            float xx[4]; int gx[4];
#pragma unroll
            for (int r = 0; r < 4; ++r) { xx[r] = x2s[pbase + r]; gx[r] = sb + pbase + r; }
#pragma unroll
            for (int j = 0; j < 4; ++j)
#pragma unroll
                for (int r = 0; r < 4; ++r) {
                    float s = 2.f * acc[i][j][r] - xx[r];
                    if (s > ss[j][KTOP - 1]) {             // in-lane arrival is ascending idx
                        ss[j][KTOP - 1] = s; si[j][KTOP - 1] = gx[r];
#pragma unroll
                        for (int k = KTOP - 1; k > 0; --k) {
                            if (ss[j][k] > ss[j][k - 1]) {
                                float tf = ss[j][k]; ss[j][k] = ss[j][k - 1]; ss[j][k - 1] = tf;
                                int   tg = si[j][k]; si[j][k] = si[j][k - 1]; si[j][k - 1] = tg;
                            }
                        }
                    }
                }
        }
    }

    // merge the 4 quad-lanes holding each (query, col) and write per-part top-5
#pragma unroll
    for (int j = 0; j < 4; ++j) { merge_xor(ss[j], si[j], 16); merge_xor(ss[j], si[j], 32); }
    if (quad == 0) {
#pragma unroll
        for (int j = 0; j < 4; ++j) {
            int qg = qb * QBLK + wave * 64 + j * 16 + col;
            size_t base = ((size_t)qg * NPART + part) * KTOP;
#pragma unroll
            for (int k = 0; k < KTOP; ++k) { cand_s[base + k] = ss[j][k]; cand_i[base + k] = si[j][k]; }
        }
    }
}

// ---- finalize: pool 640 cands -> approx top-16 -> exact fp32 rescore -> vote
__launch_bounds__(256)
__global__ void finalize(const float* __restrict__ Q, const float* __restrict__ X,
                         const float* __restrict__ x2g, const int* __restrict__ Y,
                         const float* __restrict__ cand_s, const int* __restrict__ cand_i,
                         float* __restrict__ out) {
    __shared__ float scs[4][96];
    __shared__ int   sis[4][96];
    const int t = threadIdx.x, lane = t & 63, w = t >> 6;
    const int q = blockIdx.x * 4 + w;

    // phase 1: 16 lanes x 40 contiguous candidates -> local top-5
    if (lane < 16) {
        float ls[KTOP]; int li[KTOP];
#pragma unroll
        for (int k = 0; k < KTOP; ++k) { ls[k] = -INFINITY; li[k] = 0x7fffffff; }
        const float* cs = cand_s + (size_t)q * NPART * KTOP + lane * 40;
        const int*   ci = cand_i + (size_t)q * NPART * KTOP + lane * 40;
        for (int c = 0; c < 40; ++c) {
            float s = cs[c]; int p = ci[c];
            if (s > ls[KTOP - 1] || (s == ls[KTOP - 1] && p < li[KTOP - 1])) {
                ls[KTOP - 1] = s; li[KTOP - 1] = p;
#pragma unroll
                for (int k = KTOP - 1; k > 0; --k) {
                    bool up = (ls[k] > ls[k - 1]) || (ls[k] == ls[k - 1] && li[k] < li[k - 1]);
                    if (up) {
                        float tf = ls[k]; ls[k] = ls[k - 1]; ls[k - 1] = tf;
                        int   tg = li[k]; li[k] = li[k - 1]; li[k - 1] = tg;
                    }
                }
            }
        }
#pragma unroll
        for (int k = 0; k < KTOP; ++k) { scs[w][lane * KTOP + k] = ls[k]; sis[w][lane * KTOP + k] = li[k]; }
    }
    __syncthreads();
    // phase 2: lane 0 picks approx top-16 of 80
    if (lane == 0) {
        float bs[16]; int bx[16];
#pragma unroll
        for (int m = 0; m < 16; ++m) { bs[m] = -INFINITY; bx[m] = 0x7fffffff; }
        for (int c = 0; c < 80; ++c) {
            float s = scs[w][c]; int p = sis[w][c];
            if (s > bs[15] || (s == bs[15] && p < bx[15])) {
                bs[15] = s; bx[15] = p;
#pragma unroll
                for (int m = 15; m > 0; --m) {
                    bool up = (bs[m] > bs[m - 1]) || (bs[m] == bs[m - 1] && bx[m] < bx[m - 1]);
                    if (up) {
                        float tf = bs[m]; bs[m] = bs[m - 1]; bs[m - 1] = tf;
                        int   tg = bx[m]; bx[m] = bx[m - 1]; bx[m - 1] = tg;
                    }
                }
            }
        }
#pragma unroll
        for (int m = 0; m < 16; ++m) sis[w][80 + m] = bx[m];
    }
    __syncthreads();
    // phase 3: exact fp32 rescore of 16 candidates (4 lanes x 128 dims each)
    const int c = lane & 15, seg = lane >> 4;
    int idx = sis[w][80 + c];
    const float4* xr = (const float4*)(X + (size_t)idx * D);
    const float4* qr = (const float4*)(Q + (size_t)q * D);
    float d = 0.f;
    for (int u = seg * 32; u < seg * 32 + 32; ++u) {
        float4 a = qr[u], b = xr[u];
        d = fmaf(a.x, b.x, d); d = fmaf(a.y, b.y, d);
        d = fmaf(a.z, b.z, d); d = fmaf(a.w, b.w, d);
    }
    d += __shfl_xor(d, 16);
    d += __shfl_xor(d, 32);
    float sc = 2.f * d - x2g[idx];
    if (seg == 0) scs[w][80 + c] = sc;
    __syncthreads();
    // phase 4: exact top-5 of 16, vote
    if (lane == 0) {
        float bs[KTOP]; int bx[KTOP];
#pragma unroll
        for (int k = 0; k < KTOP; ++k) { bs[k] = -INFINITY; bx[k] = 0x7fffffff; }
        for (int c2 = 0; c2 < 16; ++c2) {
            float s = scs[w][80 + c2]; int p = sis[w][80 + c2];
            if (s > bs[KTOP - 1] || (s == bs[KTOP - 1] && p < bx[KTOP - 1])) {
                bs[KTOP - 1] = s; bx[KTOP - 1] = p;
#pragma unroll
                for (int k = KTOP - 1; k > 0; --k) {
                    bool up = (bs[k] > bs[k - 1]) || (bs[k] == bs[k - 1] && bx[k] < bx[k - 1]);
                    if (up) {
                        float tf = bs[k]; bs[k] = bs[k - 1]; bs[k - 1] = tf;
                        int   tg = bx[k]; bx[k] = bx[k - 1]; bx[k - 1] = tg;
                    }
                }
            }
        }
        float sum = 0.f;
#pragma unroll
        for (int k = 0; k < KTOP; ++k) sum += (float)Y[bx[k]];
        out[2 * q]     = sum * 0.2f;
        out[2 * q + 1] = 0.f;
    }
}

extern "C" void kernel_launch(void* const* d_in, const int* in_sizes, int n_in,
                              void* d_out, int out_size, void* d_ws, size_t ws_size,
                              hipStream_t stream) {
    const float* Qf = (const float*)d_in[0];
    const float* Xf = (const float*)d_in[1];
    const int*   Y  = (const int*)d_in[2];
    float* out = (float*)d_out;

    char* ws = (char*)d_ws;
    u16*   Qbf    = (u16*)ws;                            // 2,097,152 B
    float* x2     = (float*)(ws + 2097152);              //   400,000 B
    float* cand_s = (float*)(ws + 2497152);              // 5,242,880 B
    int*   cand_i = (int*)  (ws + 7740032);              // 5,242,880 B  (end ~13 MB)

    hipLaunchKernelGGL(prep_q,   dim3(512),      dim3(256), 0, stream, Qf, Qbf);
    hipLaunchKernelGGL(x2_kernel,dim3(N / 4),    dim3(256), 0, stream, Xf, x2);
    hipLaunchKernelGGL(knn_mfma, dim3(8, NPART), dim3(256), 0, stream, Xf, Qbf, x2, cand_s, cand_i);
    hipLaunchKernelGGL(finalize, dim3(B / 4),    dim3(256), 0, stream, Qf, Xf, x2, Y, cand_s, cand_i, out);
}

// Round 3
// 1005.655 us; speedup vs baseline: 8.4791x; 1.0182x over previous
//
#include <hip/hip_runtime.h>
#include <math.h>

typedef unsigned int   u32;
typedef unsigned short u16;
typedef short short8 __attribute__((ext_vector_type(8)));   // 8 bf16 = 4 VGPRs
typedef float f32x4  __attribute__((ext_vector_type(4)));

constexpr int B     = 2048;
constexpr int D     = 512;
constexpr int N     = 100000;
constexpr int KTOP  = 5;
constexpr int NPART = 128;
constexpr int NK    = 16;                 // 512 / 32
// Big path: chunk is a multiple of 64 so subtiles align to 16-point fragment groups.
constexpr int CHUNK    = 832;             // 13 subtiles of 64
constexpr int NPTS_PAD = NPART * CHUNK;   // 106496
constexpr int NPG      = NPTS_PAD / 16;   // 6656 point-groups
constexpr int PGPART   = CHUNK / 16;      // 52
constexpr int SSTEPS   = (CHUNK / 64) * NK;  // 208 flat k-steps per part

__device__ __forceinline__ u16 f2bf(float f) {   // RNE, finite normals
    u32 u = __float_as_uint(f);
    return (u16)((u + 0x7fffu + ((u >> 16) & 1u)) >> 16);
}

__device__ __forceinline__ void gld_lds16(const void* g, void* l) {
    __builtin_amdgcn_global_load_lds((const __attribute__((address_space(1))) u32*)g,
                                     (__attribute__((address_space(3))) u32*)l, 16, 0, 0);
}

__device__ __forceinline__ void ins5(float (&s)[KTOP], int (&x)[KTOP], float v, int p) {
    if (v > s[KTOP - 1]) {                 // strict >: earlier (lower) idx wins ties
        s[KTOP - 1] = v; x[KTOP - 1] = p;
#pragma unroll
        for (int k = KTOP - 1; k > 0; --k) {
            if (s[k] > s[k - 1]) {
                float tf = s[k]; s[k] = s[k - 1]; s[k - 1] = tf;
                int   tg = x[k]; x[k] = x[k - 1]; x[k - 1] = tg;
            }
        }
    }
}

// ---- Q -> bf16 in MFMA B-frag order ---------------------------------------
__global__ void prep_q(const float* __restrict__ Q, u16* __restrict__ Qbf) {
    int tid  = blockIdx.x * 256 + threadIdx.x;     // 131072
    int q    = tid >> 6;
    int koct = tid & 63;
    const float4* src = (const float4*)(Q + (size_t)q * D + koct * 8);
    float4 a = src[0], b = src[1];
    u32 p0 = (u32)f2bf(a.x) | ((u32)f2bf(a.y) << 16);
    u32 p1 = (u32)f2bf(a.z) | ((u32)f2bf(a.w) << 16);
    u32 p2 = (u32)f2bf(b.x) | ((u32)f2bf(b.y) << 16);
    u32 p3 = (u32)f2bf(b.z) | ((u32)f2bf(b.w) << 16);
    int frag = (q >> 4) * NK + (koct >> 2);
    int lane = (q & 15) + 16 * (koct & 3);
    *(uint4*)(Qbf + (size_t)frag * 512 + lane * 8) = make_uint4(p0, p1, p2, p3);
}

// ---- X -> bf16 in MFMA A-frag order, one frag per wave, zero-padded -------
__global__ void prep_x(const float* __restrict__ X, u16* __restrict__ Xbf) {
    int f    = blockIdx.x * 4 + (threadIdx.x >> 6);   // frag = pg*NK + k0i
    int lane = threadIdx.x & 63;
    int pg   = f >> 4, k0i = f & 15;
    int point = (pg << 4) + (lane & 15);
    int k     = (k0i << 5) + ((lane >> 4) << 3);
    uint4 o = make_uint4(0u, 0u, 0u, 0u);
    if (point < N) {
        const float4* src = (const float4*)(X + (size_t)point * D + k);
        float4 a = src[0], b = src[1];
        o.x = (u32)f2bf(a.x) | ((u32)f2bf(a.y) << 16);
        o.y = (u32)f2bf(a.z) | ((u32)f2bf(a.w) << 16);
        o.z = (u32)f2bf(b.x) | ((u32)f2bf(b.y) << 16);
        o.w = (u32)f2bf(b.z) | ((u32)f2bf(b.w) << 16);
    }
    *(uint4*)(Xbf + (size_t)f * 512 + lane * 8) = o;
}

// ---- x2 = ||x||^2 (exact fp32), +INF in the padded tail -------------------
__global__ void x2_kernel(const float* __restrict__ X, float* __restrict__ x2, int total) {
    int lane = threadIdx.x & 63;
    int wid  = (int)((blockIdx.x * blockDim.x + threadIdx.x) >> 6);
    if (wid >= total) return;
    if (wid >= N) { if (lane == 0) x2[wid] = INFINITY; return; }
    const float* row = X + (size_t)wid * D;
    float s = 0.f;
    for (int c = lane; c < D; c += 64) { float v = row[c]; s = fmaf(v, v, s); }
#pragma unroll
    for (int off = 32; off > 0; off >>= 1) s += __shfl_down(s, off);
    if (lane == 0) x2[wid] = s;
}

// ---- merge two sorted-desc top-5 lists across xor-partner lanes -----------
__device__ __forceinline__ void merge_xor(float (&s)[KTOP], int (&x)[KTOP], int mask) {
    float bs[KTOP], as[KTOP]; int bx[KTOP], ax[KTOP];
#pragma unroll
    for (int k = 0; k < KTOP; ++k) {
        bs[k] = __shfl_xor(s[k], mask); bx[k] = __shfl_xor(x[k], mask);
        as[k] = s[k]; ax[k] = x[k];
    }
#pragma unroll
    for (int k = 0; k < KTOP; ++k) {
        bool ta = (as[0] > bs[0]) || ((as[0] == bs[0]) && (ax[0] < bx[0]));
        s[k] = ta ? as[0] : bs[0];
        x[k] = ta ? ax[0] : bx[0];
#pragma unroll
        for (int m = 0; m < KTOP - 1; ++m) {
            as[m] = ta ? as[m + 1] : as[m];     ax[m] = ta ? ax[m + 1] : ax[m];
            bs[m] = ta ? bs[m]     : bs[m + 1]; bx[m] = ta ? bx[m]     : bx[m + 1];
        }
        as[KTOP - 1] = ta ? -INFINITY : as[KTOP - 1];
        bs[KTOP - 1] = ta ? bs[KTOP - 1] : -INFINITY;
    }
}

// ---- big path main: all-gld_lds staging, double-buffered, 1 barrier/k-step -
__launch_bounds__(256, 3)
__global__ void knn_mfma2(const u16* __restrict__ Xbf, const u16* __restrict__ Qbf,
                          const float* __restrict__ x2g,
                          float* __restrict__ cand_s, int* __restrict__ cand_i) {
    __shared__ __attribute__((aligned(16))) u16 Afr[2][4 * 512];
    __shared__ __attribute__((aligned(16))) u16 Bfr[2][16 * 512];
    const int t    = threadIdx.x;
    const int lane = t & 63;
    const int wave = t >> 6;
    const int quad = lane >> 4;
    const int col  = lane & 15;
    const int qb   = blockIdx.x;        // 0..7
    const int part = blockIdx.y;        // 0..127
    const int pstart = part * CHUNK;
    const int pg0    = part * PGPART;

    float ss[4][KTOP]; int si[4][KTOP];
#pragma unroll
    for (int j = 0; j < 4; ++j)
#pragma unroll
        for (int k = 0; k < KTOP; ++k) { ss[j][k] = -INFINITY; si[j][k] = 0x7fffffff; }

    f32x4 acc[4][4];
#pragma unroll
    for (int i = 0; i < 4; ++i)
#pragma unroll
        for (int j = 0; j < 4; ++j) acc[i][j] = (f32x4)0.f;

    auto issue = [&](int s, int bsel) {
        int sbi = s >> 4, k0i = s & 15;
        int apg = pg0 + sbi * 4 + wave;
        gld_lds16(Xbf + (((size_t)apg << 4) + k0i) * 512 + (lane << 3), &Afr[bsel][wave * 512]);
#pragma unroll
        for (int j = 0; j < 4; ++j) {
            int qg = qb * 16 + wave * 4 + j;
            gld_lds16(Qbf + (((size_t)qg << 4) + k0i) * 512 + (lane << 3),
                      &Bfr[bsel][(wave * 4 + j) * 512]);
        }
    };

    issue(0, 0);
    for (int s = 0; s < SSTEPS; ++s) {
        const int bsel = s & 1;
        __syncthreads();                       // drains loads issued one step ago
        if (s + 1 < SSTEPS) issue(s + 1, bsel ^ 1);
        short8 af[4], bq[4];
#pragma unroll
        for (int i = 0; i < 4; ++i) af[i] = *(const short8*)&Afr[bsel][i * 512 + lane * 8];
#pragma unroll
        for (int j = 0; j < 4; ++j) bq[j] = *(const short8*)&Bfr[bsel][(wave * 4 + j) * 512 + lane * 8];
#pragma unroll
        for (int i = 0; i < 4; ++i)
#pragma unroll
            for (int j = 0; j < 4; ++j)
                acc[i][j] = __builtin_amdgcn_mfma_f32_16x16x32_bf16(af[i], bq[j], acc[i][j], 0, 0, 0);

        if ((s & 15) == 15) {                  // subtile done: select + reset acc
            int sb = pstart + (s >> 4) * 64;
#pragma unroll
            for (int i = 0; i < 4; ++i) {
                int gbase = sb + 16 * i + quad * 4;
                float4 xx = *(const float4*)(x2g + gbase);
#pragma unroll
                for (int j = 0; j < 4; ++j) {
                    float s0 = fmaf(2.f, acc[i][j][0], -xx.x);
                    float s1 = fmaf(2.f, acc[i][j][1], -xx.y);
                    float s2 = fmaf(2.f, acc[i][j][2], -xx.z);
                    float s3 = fmaf(2.f, acc[i][j][3], -xx.w);
                    float mx = fmaxf(fmaxf(s0, s1), fmaxf(s2, s3));
                    if (mx > ss[j][KTOP - 1]) {
                        ins5(ss[j], si[j], s0, gbase + 0);
                        ins5(ss[j], si[j], s1, gbase + 1);
                        ins5(ss[j], si[j], s2, gbase + 2);
                        ins5(ss[j], si[j], s3, gbase + 3);
                    }
                    acc[i][j] = (f32x4)0.f;
                }
            }
        }
    }

#pragma unroll
    for (int j = 0; j < 4; ++j) { merge_xor(ss[j], si[j], 16); merge_xor(ss[j], si[j], 32); }
    if (quad == 0) {
#pragma unroll
        for (int j = 0; j < 4; ++j) {
            int qg = qb * 256 + wave * 64 + j * 16 + col;
            size_t base = ((size_t)qg * NPART + part) * KTOP;
#pragma unroll
            for (int k = 0; k < KTOP; ++k) { cand_s[base + k] = ss[j][k]; cand_i[base + k] = si[j][k]; }
        }
    }
}

// ---- fallback main (round-2 proven path, in-loop conversion) --------------
__launch_bounds__(256)
__global__ void knn_conv(const float* __restrict__ X, const u16* __restrict__ Qbf,
                         const float* __restrict__ x2g,
                         float* __restrict__ cand_s, int* __restrict__ cand_i) {
    __shared__ __attribute__((aligned(16))) u16 Bfr[16 * 512];
    __shared__ __attribute__((aligned(16))) u16 Afr[4 * 512];
    __shared__ float x2s[64];
    const int t = threadIdx.x, lane = t & 63, wave = t >> 6;
    const int quad = lane >> 4, col = lane & 15;
    const int qb = blockIdx.x, part = blockIdx.y;
    const int pstart = part * 782;
    const int pend   = min(pstart + 782, N);

    float ss[4][KTOP]; int si[4][KTOP];
#pragma unroll
    for (int j = 0; j < 4; ++j)
#pragma unroll
        for (int k = 0; k < KTOP; ++k) { ss[j][k] = -INFINITY; si[j][k] = 0x7fffffff; }

    const int nsub = (pend - pstart + 63) / 64;
    for (int sbi = 0; sbi < nsub; ++sbi) {
        const int sb = pstart + sbi * 64;
        __syncthreads();
        if (t < 64) x2s[t] = (sb + t < pend) ? x2g[sb + t] : INFINITY;
        f32x4 acc[4][4];
#pragma unroll
        for (int i = 0; i < 4; ++i)
#pragma unroll
            for (int j = 0; j < 4; ++j) acc[i][j] = (f32x4)0.f;
        for (int k0i = 0; k0i < NK; ++k0i) {
            const int k0 = k0i * 32;
            __syncthreads();
            {
                int prow = sb + wave * 16 + col;
                if (prow >= pend) prow = pend - 1;
                const float4* src = (const float4*)(X + (size_t)prow * D + k0 + quad * 8);
                float4 a = src[0], b = src[1];
                u32 p0 = (u32)f2bf(a.x) | ((u32)f2bf(a.y) << 16);
                u32 p1 = (u32)f2bf(a.z) | ((u32)f2bf(a.w) << 16);
                u32 p2 = (u32)f2bf(b.x) | ((u32)f2bf(b.y) << 16);
                u32 p3 = (u32)f2bf(b.z) | ((u32)f2bf(b.w) << 16);
                *(uint4*)(Afr + wave * 512 + lane * 8) = make_uint4(p0, p1, p2, p3);
            }
#pragma unroll
            for (int j = 0; j < 4; ++j) {
                int qgrp = qb * 16 + wave * 4 + j;
                gld_lds16(Qbf + ((size_t)qgrp * NK + k0i) * 512 + lane * 8, (void*)(Bfr + (wave * 4 + j) * 512));
            }
            __syncthreads();
            short8 af[4], bq[4];
#pragma unroll
            for (int i = 0; i < 4; ++i) af[i] = *(const short8*)(Afr + i * 512 + lane * 8);
#pragma unroll
            for (int j = 0; j < 4; ++j) bq[j] = *(const short8*)(Bfr + (wave * 4 + j) * 512 + lane * 8);
#pragma unroll
            for (int i = 0; i < 4; ++i)
#pragma unroll
                for (int j = 0; j < 4; ++j)
                    acc[i][j] = __builtin_amdgcn_mfma_f32_16x16x32_bf16(af[i], bq[j], acc[i][j], 0, 0, 0);
        }
#pragma unroll
        for (int i = 0; i < 4; ++i) {
            int pb = 16 * i + quad * 4;
#pragma unroll
            for (int j = 0; j < 4; ++j)
#pragma unroll
                for (int r = 0; r < 4; ++r)
                    ins5(ss[j], si[j], 2.f * acc[i][j][r] - x2s[pb + r], sb + pb + r);
        }
    }
#pragma unroll
    for (int j = 0; j < 4; ++j) { merge_xor(ss[j], si[j], 16); merge_xor(ss[j], si[j], 32); }
    if (quad == 0) {
#pragma unroll
        for (int j = 0; j < 4; ++j) {
            int qg = qb * 256 + wave * 64 + j * 16 + col;
            size_t base = ((size_t)qg * NPART + part) * KTOP;
#pragma unroll
            for (int k = 0; k < KTOP; ++k) { cand_s[base + k] = ss[j][k]; cand_i[base + k] = si[j][k]; }
        }
    }
}

// ---- finalize: pool 640 cands -> approx top-16 -> exact fp32 rescore -> vote
__launch_bounds__(256)
__global__ void finalize(const float* __restrict__ Q, const float* __restrict__ X,
                         const float* __restrict__ x2g, const int* __restrict__ Y,
                         const float* __restrict__ cand_s, const int* __restrict__ cand_i,
                         float* __restrict__ out) {
    __shared__ float scs[4][96];
    __shared__ int   sis[4][96];
    const int t = threadIdx.x, lane = t & 63, w = t >> 6;
    const int q = blockIdx.x * 4 + w;

    if (lane < 16) {
        float ls[KTOP]; int li[KTOP];
#pragma unroll
        for (int k = 0; k < KTOP; ++k) { ls[k] = -INFINITY; li[k] = 0x7fffffff; }
        const float* cs = cand_s + (size_t)q * NPART * KTOP + lane * 40;
        const int*   ci = cand_i + (size_t)q * NPART * KTOP + lane * 40;
        for (int c = 0; c < 40; ++c) {
            float s = cs[c]; int p = ci[c];
            if (s > ls[KTOP - 1] || (s == ls[KTOP - 1] && p < li[KTOP - 1])) {
                ls[KTOP - 1] = s; li[KTOP - 1] = p;
#pragma unroll
                for (int k = KTOP - 1; k > 0; --k) {
                    bool up = (ls[k] > ls[k - 1]) || (ls[k] == ls[k - 1] && li[k] < li[k - 1]);
                    if (up) {
                        float tf = ls[k]; ls[k] = ls[k - 1]; ls[k - 1] = tf;
                        int   tg = li[k]; li[k] = li[k - 1]; li[k - 1] = tg;
                    }
                }
            }
        }
#pragma unroll
        for (int k = 0; k < KTOP; ++k) { scs[w][lane * KTOP + k] = ls[k]; sis[w][lane * KTOP + k] = li[k]; }
    }
    __syncthreads();
    if (lane == 0) {
        float bs[16]; int bx[16];
#pragma unroll
        for (int m = 0; m < 16; ++m) { bs[m] = -INFINITY; bx[m] = 0x7fffffff; }
        for (int c = 0; c < 80; ++c) {
            float s = scs[w][c]; int p = sis[w][c];
            if (s > bs[15] || (s == bs[15] && p < bx[15])) {
                bs[15] = s; bx[15] = p;
#pragma unroll
                for (int m = 15; m > 0; --m) {
                    bool up = (bs[m] > bs[m - 1]) || (bs[m] == bs[m - 1] && bx[m] < bx[m - 1]);
                    if (up) {
                        float tf = bs[m]; bs[m] = bs[m - 1]; bs[m - 1] = tf;
                        int   tg = bx[m]; bx[m] = bx[m - 1]; bx[m - 1] = tg;
                    }
                }
            }
        }
#pragma unroll
        for (int m = 0; m < 16; ++m) sis[w][80 + m] = bx[m];
    }
    __syncthreads();
    const int c = lane & 15, seg = lane >> 4;
    int idx = sis[w][80 + c];
    const float4* xr = (const float4*)(X + (size_t)idx * D);
    const float4* qr = (const float4*)(Q + (size_t)q * D);
    float d = 0.f;
    for (int u = seg * 32; u < seg * 32 + 32; ++u) {
        float4 a = qr[u], b = xr[u];
        d = fmaf(a.x, b.x, d); d = fmaf(a.y, b.y, d);
        d = fmaf(a.z, b.z, d); d = fmaf(a.w, b.w, d);
    }
    d += __shfl_xor(d, 16);
    d += __shfl_xor(d, 32);
    float sc = 2.f * d - x2g[idx];
    if (seg == 0) scs[w][80 + c] = sc;
    __syncthreads();
    if (lane == 0) {
        float bs[KTOP]; int bx[KTOP];
#pragma unroll
        for (int k = 0; k < KTOP; ++k) { bs[k] = -INFINITY; bx[k] = 0x7fffffff; }
        for (int c2 = 0; c2 < 16; ++c2) {
            float s = scs[w][80 + c2]; int p = sis[w][80 + c2];
            if (s > bs[KTOP - 1] || (s == bs[KTOP - 1] && p < bx[KTOP - 1])) {
                bs[KTOP - 1] = s; bx[KTOP - 1] = p;
#pragma unroll
                for (int k = KTOP - 1; k > 0; --k) {
                    bool up = (bs[k] > bs[k - 1]) || (bs[k] == bs[k - 1] && bx[k] < bx[k - 1]);
                    if (up) {
                        float tf = bs[k]; bs[k] = bs[k - 1]; bs[k - 1] = tf;
                        int   tg = bx[k]; bx[k] = bx[k - 1]; bx[k - 1] = tg;
                    }
                }
            }
        }
        float sum = 0.f;
#pragma unroll
        for (int k = 0; k < KTOP; ++k) sum += (float)Y[bx[k]];
        out[2 * q]     = sum * 0.2f;
        out[2 * q + 1] = 0.f;
    }
}

extern "C" void kernel_launch(void* const* d_in, const int* in_sizes, int n_in,
                              void* d_out, int out_size, void* d_ws, size_t ws_size,
                              hipStream_t stream) {
    const float* Qf = (const float*)d_in[0];
    const float* Xf = (const float*)d_in[1];
    const int*   Y  = (const int*)d_in[2];
    float* out = (float*)d_out;
    char* ws = (char*)d_ws;

    constexpr size_t XBF_B  = (size_t)NPG * NK * 1024;          // 109,051,904
    constexpr size_t QBF_B  = 2097152;
    constexpr size_t X2_B   = (size_t)NPTS_PAD * 4;             //    425,984
    constexpr size_t CAND_B = (size_t)B * NPART * KTOP * 4;     //  5,242,880
    constexpr size_t NEED   = XBF_B + QBF_B + X2_B + 2 * CAND_B;

    if (ws_size >= NEED) {
        u16*   Xbf    = (u16*)ws;
        u16*   Qbf    = (u16*)(ws + XBF_B);
        float* x2     = (float*)(ws + XBF_B + QBF_B);
        float* cand_s = (float*)(ws + XBF_B + QBF_B + X2_B);
        int*   cand_i = (int*)  (ws + XBF_B + QBF_B + X2_B + CAND_B);
        hipLaunchKernelGGL(prep_q,    dim3(512),          dim3(256), 0, stream, Qf, Qbf);
        hipLaunchKernelGGL(prep_x,    dim3(NPG * NK / 4), dim3(256), 0, stream, Xf, Xbf);
        hipLaunchKernelGGL(x2_kernel, dim3(NPTS_PAD / 4), dim3(256), 0, stream, Xf, x2, NPTS_PAD);
        hipLaunchKernelGGL(knn_mfma2, dim3(8, NPART),     dim3(256), 0, stream, Xbf, Qbf, x2, cand_s, cand_i);
        hipLaunchKernelGGL(finalize,  dim3(B / 4),        dim3(256), 0, stream, Qf, Xf, x2, Y, cand_s, cand_i, out);
    } else {                                   // round-2 proven fallback
        u16*   Qbf    = (u16*)ws;
        float* x2     = (float*)(ws + 2097152);
        float* cand_s = (float*)(ws + 2497152);
        int*   cand_i = (int*)  (ws + 7740032);
        hipLaunchKernelGGL(prep_q,    dim3(512),      dim3(256), 0, stream, Qf, Qbf);
        hipLaunchKernelGGL(x2_kernel, dim3(N / 4),    dim3(256), 0, stream, Xf, x2, N);
        hipLaunchKernelGGL(knn_conv,  dim3(8, NPART), dim3(256), 0, stream, Xf, Qbf, x2, cand_s, cand_i);
        hipLaunchKernelGGL(finalize,  dim3(B / 4),    dim3(256), 0, stream, Qf, Xf, x2, Y, cand_s, cand_i, out);
    }
}

// Round 4
// 699.486 us; speedup vs baseline: 12.1904x; 1.4377x over previous
//
#include <hip/hip_runtime.h>
#include <math.h>

typedef unsigned int   u32;
typedef unsigned short u16;
typedef short short8 __attribute__((ext_vector_type(8)));   // 8 bf16 = 4 VGPRs
typedef float f32x4  __attribute__((ext_vector_type(4)));

constexpr int B    = 2048;
constexpr int D    = 512;
constexpr int N    = 100000;
constexpr int KTOP = 5;
constexpr int NK   = 16;                  // 512 / 32

// Big path: Q-resident kernel. 16-point groups (pg) are the N-tile unit.
constexpr int NPART    = 32;
constexpr int CHUNK    = 3136;            // 196 pgs of 16; 32*3136 = 100352 >= N
constexpr int PGPART   = CHUNK / 16;      // 196
constexpr int NPTS_PAD = NPART * CHUNK;   // 100352
constexpr int NPG      = NPTS_PAD / 16;   // 6272

__device__ __forceinline__ u16 f2bf(float f) {   // RNE, finite normals
    u32 u = __float_as_uint(f);
    return (u16)((u + 0x7fffu + ((u >> 16) & 1u)) >> 16);
}

__device__ __forceinline__ void gld_lds16(const void* g, void* l) {
    __builtin_amdgcn_global_load_lds((const __attribute__((address_space(1))) u32*)g,
                                     (__attribute__((address_space(3))) u32*)l, 16, 0, 0);
}

__device__ __forceinline__ void ins5(float (&s)[KTOP], int (&x)[KTOP], float v, int p) {
    if (v > s[KTOP - 1]) {                 // strict >: earlier (lower) idx wins ties
        s[KTOP - 1] = v; x[KTOP - 1] = p;
#pragma unroll
        for (int k = KTOP - 1; k > 0; --k) {
            if (s[k] > s[k - 1]) {
                float tf = s[k]; s[k] = s[k - 1]; s[k - 1] = tf;
                int   tg = x[k]; x[k] = x[k - 1]; x[k - 1] = tg;
            }
        }
    }
}

__device__ __forceinline__ void merge_xor(float (&s)[KTOP], int (&x)[KTOP], int mask) {
    float bs[KTOP], as[KTOP]; int bx[KTOP], ax[KTOP];
#pragma unroll
    for (int k = 0; k < KTOP; ++k) {
        bs[k] = __shfl_xor(s[k], mask); bx[k] = __shfl_xor(x[k], mask);
        as[k] = s[k]; ax[k] = x[k];
    }
#pragma unroll
    for (int k = 0; k < KTOP; ++k) {
        bool ta = (as[0] > bs[0]) || ((as[0] == bs[0]) && (ax[0] < bx[0]));
        s[k] = ta ? as[0] : bs[0];
        x[k] = ta ? ax[0] : bx[0];
#pragma unroll
        for (int m = 0; m < KTOP - 1; ++m) {
            as[m] = ta ? as[m + 1] : as[m];     ax[m] = ta ? ax[m + 1] : ax[m];
            bs[m] = ta ? bs[m]     : bs[m + 1]; bx[m] = ta ? bx[m]     : bx[m + 1];
        }
        as[KTOP - 1] = ta ? -INFINITY : as[KTOP - 1];
        bs[KTOP - 1] = ta ? bs[KTOP - 1] : -INFINITY;
    }
}

// ---- Q -> bf16 in MFMA B-frag order (verified rounds 2/3) -----------------
__global__ void prep_q(const float* __restrict__ Q, u16* __restrict__ Qbf) {
    int tid  = blockIdx.x * 256 + threadIdx.x;     // 131072
    int q    = tid >> 6;
    int koct = tid & 63;
    const float4* src = (const float4*)(Q + (size_t)q * D + koct * 8);
    float4 a = src[0], b = src[1];
    u32 p0 = (u32)f2bf(a.x) | ((u32)f2bf(a.y) << 16);
    u32 p1 = (u32)f2bf(a.z) | ((u32)f2bf(a.w) << 16);
    u32 p2 = (u32)f2bf(b.x) | ((u32)f2bf(b.y) << 16);
    u32 p3 = (u32)f2bf(b.z) | ((u32)f2bf(b.w) << 16);
    int frag = (q >> 4) * NK + (koct >> 2);
    int lane = (q & 15) + 16 * (koct & 3);
    *(uint4*)(Qbf + (size_t)frag * 512 + lane * 8) = make_uint4(p0, p1, p2, p3);
}

// ---- X -> bf16 A-frags (layout verified round 3) + fused x2 ---------------
__global__ void prep_x2(const float* __restrict__ X, u16* __restrict__ Xbf,
                        float* __restrict__ x2) {
    __shared__ float psum[4][16];
    const int t = threadIdx.x, lane = t & 63, wave = t >> 6;
    const int pg    = blockIdx.x;                 // 0..NPG-1
    const int point = pg * 16 + (lane & 15);
    float ssum = 0.f;
#pragma unroll
    for (int u = 0; u < 4; ++u) {
        int k0i = wave * 4 + u;
        int k   = k0i * 32 + ((lane >> 4) << 3);
        uint4 o = make_uint4(0u, 0u, 0u, 0u);
        if (point < N) {
            const float4* src = (const float4*)(X + (size_t)point * D + k);
            float4 a = src[0], b = src[1];
            ssum = fmaf(a.x, a.x, ssum); ssum = fmaf(a.y, a.y, ssum);
            ssum = fmaf(a.z, a.z, ssum); ssum = fmaf(a.w, a.w, ssum);
            ssum = fmaf(b.x, b.x, ssum); ssum = fmaf(b.y, b.y, ssum);
            ssum = fmaf(b.z, b.z, ssum); ssum = fmaf(b.w, b.w, ssum);
            o.x = (u32)f2bf(a.x) | ((u32)f2bf(a.y) << 16);
            o.y = (u32)f2bf(a.z) | ((u32)f2bf(a.w) << 16);
            o.z = (u32)f2bf(b.x) | ((u32)f2bf(b.y) << 16);
            o.w = (u32)f2bf(b.z) | ((u32)f2bf(b.w) << 16);
        }
        *(uint4*)(Xbf + ((size_t)pg * 16 + k0i) * 512 + lane * 8) = o;
    }
    ssum += __shfl_xor(ssum, 16);
    ssum += __shfl_xor(ssum, 32);
    if (lane < 16) psum[wave][lane] = ssum;
    __syncthreads();
    if (t < 16) {
        float s = psum[0][t] + psum[1][t] + psum[2][t] + psum[3][t];
        x2[pg * 16 + t] = (pg * 16 + t < N) ? s : INFINITY;
    }
}

// ---- x2 (fallback path only) ----------------------------------------------
__global__ void x2_kernel(const float* __restrict__ X, float* __restrict__ x2, int total) {
    int lane = threadIdx.x & 63;
    int wid  = (int)((blockIdx.x * blockDim.x + threadIdx.x) >> 6);
    if (wid >= total) return;
    if (wid >= N) { if (lane == 0) x2[wid] = INFINITY; return; }
    const float* row = X + (size_t)wid * D;
    float s = 0.f;
    for (int c = lane; c < D; c += 64) { float v = row[c]; s = fmaf(v, v, s); }
#pragma unroll
    for (int off = 32; off > 0; off >>= 1) s += __shfl_down(s, off);
    if (lane == 0) x2[wid] = s;
}

// ---- main: Q resident in registers; X streams through LDS -----------------
__launch_bounds__(256, 2)
__global__ void knn_qreg(const u16* __restrict__ Xbf, const u16* __restrict__ Qbf,
                         const float* __restrict__ x2g,
                         float* __restrict__ cand_s, int* __restrict__ cand_i) {
    __shared__ __attribute__((aligned(16))) u16 Afr[2][16 * 512];   // 2 x 16KB
    const int t    = threadIdx.x;
    const int lane = t & 63;
    const int wave = t >> 6;
    const int quad = lane >> 4;
    const int col  = lane & 15;
    const int qb   = blockIdx.x;          // 0..15 (128 queries each)
    const int part = blockIdx.y;          // 0..31
    const int pg0    = part * PGPART;
    const int pstart = part * CHUNK;

    // Resident Q: 2 query-groups x 16 k-steps = 128 VGPRs
    short8 bq[2][16];
#pragma unroll
    for (int j = 0; j < 2; ++j) {
        int qg = qb * 8 + wave * 2 + j;
#pragma unroll
        for (int k0i = 0; k0i < 16; ++k0i)
            bq[j][k0i] = *(const short8*)(Qbf + ((size_t)qg * 16 + k0i) * 512 + lane * 8);
    }

    float ss[2][KTOP]; int si[2][KTOP];
#pragma unroll
    for (int j = 0; j < 2; ++j)
#pragma unroll
        for (int k = 0; k < KTOP; ++k) { ss[j][k] = -INFINITY; si[j][k] = 0x7fffffff; }

    auto issue = [&](int pgi, int bsel) {
        const u16* src = Xbf + ((size_t)(pg0 + pgi) * 16 + wave * 4) * 512 + lane * 8;
        u16* dst = Afr[bsel] + (wave * 4) * 512;       // wave-uniform LDS base
#pragma unroll
        for (int f = 0; f < 4; ++f)
            gld_lds16(src + f * 512, dst + f * 512);
    };

    issue(0, 0);
    for (int pgi = 0; pgi < PGPART; ++pgi) {
        const int bsel = pgi & 1;
        __syncthreads();                               // drains prior-pg gld_lds
        if (pgi + 1 < PGPART) issue(pgi + 1, bsel ^ 1);
        const int P = pstart + pgi * 16;
        float4 xx = *(const float4*)(x2g + P + quad * 4);

        f32x4 acc0 = (f32x4)0.f, acc1 = (f32x4)0.f;
#pragma unroll
        for (int k0i = 0; k0i < 16; ++k0i) {
            short8 af = *(const short8*)&Afr[bsel][k0i * 512 + lane * 8];
            acc0 = __builtin_amdgcn_mfma_f32_16x16x32_bf16(af, bq[0][k0i], acc0, 0, 0, 0);
            acc1 = __builtin_amdgcn_mfma_f32_16x16x32_bf16(af, bq[1][k0i], acc1, 0, 0, 0);
        }
        // C layout: col=lane&15 (query), row=quad*4+reg (point)
        const int gbase = P + quad * 4;
        {
            float s0 = fmaf(2.f, acc0[0], -xx.x);
            float s1 = fmaf(2.f, acc0[1], -xx.y);
            float s2 = fmaf(2.f, acc0[2], -xx.z);
            float s3 = fmaf(2.f, acc0[3], -xx.w);
            float mx = fmaxf(fmaxf(s0, s1), fmaxf(s2, s3));
            if (mx > ss[0][KTOP - 1]) {
                ins5(ss[0], si[0], s0, gbase + 0);
                ins5(ss[0], si[0], s1, gbase + 1);
                ins5(ss[0], si[0], s2, gbase + 2);
                ins5(ss[0], si[0], s3, gbase + 3);
            }
        }
        {
            float s0 = fmaf(2.f, acc1[0], -xx.x);
            float s1 = fmaf(2.f, acc1[1], -xx.y);
            float s2 = fmaf(2.f, acc1[2], -xx.z);
            float s3 = fmaf(2.f, acc1[3], -xx.w);
            float mx = fmaxf(fmaxf(s0, s1), fmaxf(s2, s3));
            if (mx > ss[1][KTOP - 1]) {
                ins5(ss[1], si[1], s0, gbase + 0);
                ins5(ss[1], si[1], s1, gbase + 1);
                ins5(ss[1], si[1], s2, gbase + 2);
                ins5(ss[1], si[1], s3, gbase + 3);
            }
        }
    }

#pragma unroll
    for (int j = 0; j < 2; ++j) { merge_xor(ss[j], si[j], 16); merge_xor(ss[j], si[j], 32); }
    if (quad == 0) {
#pragma unroll
        for (int j = 0; j < 2; ++j) {
            int q = qb * 128 + wave * 32 + j * 16 + col;
            size_t base = ((size_t)q * NPART + part) * KTOP;
#pragma unroll
            for (int k = 0; k < KTOP; ++k) { cand_s[base + k] = ss[j][k]; cand_i[base + k] = si[j][k]; }
        }
    }
}

// ---- fallback main (round-2/3 proven path, in-loop conversion) ------------
__launch_bounds__(256)
__global__ void knn_conv(const float* __restrict__ X, const u16* __restrict__ Qbf,
                         const float* __restrict__ x2g,
                         float* __restrict__ cand_s, int* __restrict__ cand_i) {
    __shared__ __attribute__((aligned(16))) u16 Bfr[16 * 512];
    __shared__ __attribute__((aligned(16))) u16 Afr[4 * 512];
    __shared__ float x2s[64];
    const int t = threadIdx.x, lane = t & 63, wave = t >> 6;
    const int quad = lane >> 4, col = lane & 15;
    const int qb = blockIdx.x, part = blockIdx.y;
    const int pstart = part * 782;
    const int pend   = min(pstart + 782, N);

    float ss[4][KTOP]; int si[4][KTOP];
#pragma unroll
    for (int j = 0; j < 4; ++j)
#pragma unroll
        for (int k = 0; k < KTOP; ++k) { ss[j][k] = -INFINITY; si[j][k] = 0x7fffffff; }

    const int nsub = (pend - pstart + 63) / 64;
    for (int sbi = 0; sbi < nsub; ++sbi) {
        const int sb = pstart + sbi * 64;
        __syncthreads();
        if (t < 64) x2s[t] = (sb + t < pend) ? x2g[sb + t] : INFINITY;
        f32x4 acc[4][4];
#pragma unroll
        for (int i = 0; i < 4; ++i)
#pragma unroll
            for (int j = 0; j < 4; ++j) acc[i][j] = (f32x4)0.f;
        for (int k0i = 0; k0i < NK; ++k0i) {
            const int k0 = k0i * 32;
            __syncthreads();
            {
                int prow = sb + wave * 16 + col;
                if (prow >= pend) prow = pend - 1;
                const float4* src = (const float4*)(X + (size_t)prow * D + k0 + quad * 8);
                float4 a = src[0], b = src[1];
                u32 p0 = (u32)f2bf(a.x) | ((u32)f2bf(a.y) << 16);
                u32 p1 = (u32)f2bf(a.z) | ((u32)f2bf(a.w) << 16);
                u32 p2 = (u32)f2bf(b.x) | ((u32)f2bf(b.y) << 16);
                u32 p3 = (u32)f2bf(b.z) | ((u32)f2bf(b.w) << 16);
                *(uint4*)(Afr + wave * 512 + lane * 8) = make_uint4(p0, p1, p2, p3);
            }
#pragma unroll
            for (int j = 0; j < 4; ++j) {
                int qgrp = qb * 16 + wave * 4 + j;
                gld_lds16(Qbf + ((size_t)qgrp * NK + k0i) * 512 + lane * 8,
                          (void*)(Bfr + (wave * 4 + j) * 512));
            }
            __syncthreads();
            short8 af[4], bqf[4];
#pragma unroll
            for (int i = 0; i < 4; ++i) af[i] = *(const short8*)(Afr + i * 512 + lane * 8);
#pragma unroll
            for (int j = 0; j < 4; ++j) bqf[j] = *(const short8*)(Bfr + (wave * 4 + j) * 512 + lane * 8);
#pragma unroll
            for (int i = 0; i < 4; ++i)
#pragma unroll
                for (int j = 0; j < 4; ++j)
                    acc[i][j] = __builtin_amdgcn_mfma_f32_16x16x32_bf16(af[i], bqf[j], acc[i][j], 0, 0, 0);
        }
#pragma unroll
        for (int i = 0; i < 4; ++i) {
            int pb = 16 * i + quad * 4;
#pragma unroll
            for (int j = 0; j < 4; ++j)
#pragma unroll
                for (int r = 0; r < 4; ++r)
                    ins5(ss[j], si[j], 2.f * acc[i][j][r] - x2s[pb + r], sb + pb + r);
        }
    }
#pragma unroll
    for (int j = 0; j < 4; ++j) { merge_xor(ss[j], si[j], 16); merge_xor(ss[j], si[j], 32); }
    if (quad == 0) {
#pragma unroll
        for (int j = 0; j < 4; ++j) {
            int qg = qb * 256 + wave * 64 + j * 16 + col;
            size_t base = ((size_t)qg * 128 + part) * KTOP;
#pragma unroll
            for (int k = 0; k < KTOP; ++k) { cand_s[base + k] = ss[j][k]; cand_i[base + k] = si[j][k]; }
        }
    }
}

// ---- finalize: pool npart*5 cands -> approx top-16 -> exact rescore -> vote
__launch_bounds__(256)
__global__ void finalize(const float* __restrict__ Q, const float* __restrict__ X,
                         const float* __restrict__ x2g, const int* __restrict__ Y,
                         const float* __restrict__ cand_s, const int* __restrict__ cand_i,
                         float* __restrict__ out, int npart) {
    __shared__ float scs[4][96];
    __shared__ int   sis[4][96];
    const int t = threadIdx.x, lane = t & 63, w = t >> 6;
    const int q = blockIdx.x * 4 + w;
    const int perlane = npart * KTOP / 16;

    if (lane < 16) {
        float ls[KTOP]; int li[KTOP];
#pragma unroll
        for (int k = 0; k < KTOP; ++k) { ls[k] = -INFINITY; li[k] = 0x7fffffff; }
        const float* cs = cand_s + (size_t)q * npart * KTOP + lane * perlane;
        const int*   ci = cand_i + (size_t)q * npart * KTOP + lane * perlane;
        for (int c = 0; c < perlane; ++c) {
            float s = cs[c]; int p = ci[c];
            if (s > ls[KTOP - 1] || (s == ls[KTOP - 1] && p < li[KTOP - 1])) {
                ls[KTOP - 1] = s; li[KTOP - 1] = p;
#pragma unroll
                for (int k = KTOP - 1; k > 0; --k) {
                    bool up = (ls[k] > ls[k - 1]) || (ls[k] == ls[k - 1] && li[k] < li[k - 1]);
                    if (up) {
                        float tf = ls[k]; ls[k] = ls[k - 1]; ls[k - 1] = tf;
                        int   tg = li[k]; li[k] = li[k - 1]; li[k - 1] = tg;
                    }
                }
            }
        }
#pragma unroll
        for (int k = 0; k < KTOP; ++k) { scs[w][lane * KTOP + k] = ls[k]; sis[w][lane * KTOP + k] = li[k]; }
    }
    __syncthreads();
    if (lane == 0) {
        float bs[16]; int bx[16];
#pragma unroll
        for (int m = 0; m < 16; ++m) { bs[m] = -INFINITY; bx[m] = 0x7fffffff; }
        for (int c = 0; c < 80; ++c) {
            float s = scs[w][c]; int p = sis[w][c];
            if (s > bs[15] || (s == bs[15] && p < bx[15])) {
                bs[15] = s; bx[15] = p;
#pragma unroll
                for (int m = 15; m > 0; --m) {
                    bool up = (bs[m] > bs[m - 1]) || (bs[m] == bs[m - 1] && bx[m] < bx[m - 1]);
                    if (up) {
                        float tf = bs[m]; bs[m] = bs[m - 1]; bs[m - 1] = tf;
                        int   tg = bx[m]; bx[m] = bx[m - 1]; bx[m - 1] = tg;
                    }
                }
            }
        }
#pragma unroll
        for (int m = 0; m < 16; ++m) sis[w][80 + m] = bx[m];
    }
    __syncthreads();
    const int c = lane & 15, seg = lane >> 4;
    int idx = sis[w][80 + c];
    const float4* xr = (const float4*)(X + (size_t)idx * D);
    const float4* qr = (const float4*)(Q + (size_t)q * D);
    float d = 0.f;
    for (int u = seg * 32; u < seg * 32 + 32; ++u) {
        float4 a = qr[u], b = xr[u];
        d = fmaf(a.x, b.x, d); d = fmaf(a.y, b.y, d);
        d = fmaf(a.z, b.z, d); d = fmaf(a.w, b.w, d);
    }
    d += __shfl_xor(d, 16);
    d += __shfl_xor(d, 32);
    float sc = 2.f * d - x2g[idx];
    if (seg == 0) scs[w][80 + c] = sc;
    __syncthreads();
    if (lane == 0) {
        float bs[KTOP]; int bx[KTOP];
#pragma unroll
        for (int k = 0; k < KTOP; ++k) { bs[k] = -INFINITY; bx[k] = 0x7fffffff; }
        for (int c2 = 0; c2 < 16; ++c2) {
            float s = scs[w][80 + c2]; int p = sis[w][80 + c2];
            if (s > bs[KTOP - 1] || (s == bs[KTOP - 1] && p < bx[KTOP - 1])) {
                bs[KTOP - 1] = s; bx[KTOP - 1] = p;
#pragma unroll
                for (int k = KTOP - 1; k > 0; --k) {
                    bool up = (bs[k] > bs[k - 1]) || (bs[k] == bs[k - 1] && bx[k] < bx[k - 1]);
                    if (up) {
                        float tf = bs[k]; bs[k] = bs[k - 1]; bs[k - 1] = tf;
                        int   tg = bx[k]; bx[k] = bx[k - 1]; bx[k - 1] = tg;
                    }
                }
            }
        }
        float sum = 0.f;
#pragma unroll
        for (int k = 0; k < KTOP; ++k) sum += (float)Y[bx[k]];
        out[2 * q]     = sum * 0.2f;
        out[2 * q + 1] = 0.f;
    }
}

extern "C" void kernel_launch(void* const* d_in, const int* in_sizes, int n_in,
                              void* d_out, int out_size, void* d_ws, size_t ws_size,
                              hipStream_t stream) {
    const float* Qf = (const float*)d_in[0];
    const float* Xf = (const float*)d_in[1];
    const int*   Y  = (const int*)d_in[2];
    float* out = (float*)d_out;
    char* ws = (char*)d_ws;

    constexpr size_t XBF_B  = (size_t)NPG * NK * 1024;        // 102,760,448
    constexpr size_t QBF_B  = 2097152;
    constexpr size_t X2_B   = (size_t)NPTS_PAD * 4;           //     401,408
    constexpr size_t CAND_B = (size_t)B * NPART * KTOP * 4;   //   1,310,720
    constexpr size_t NEED   = XBF_B + QBF_B + X2_B + 2 * CAND_B;

    if (ws_size >= NEED) {
        u16*   Xbf    = (u16*)ws;
        u16*   Qbf    = (u16*)(ws + XBF_B);
        float* x2     = (float*)(ws + XBF_B + QBF_B);
        float* cand_s = (float*)(ws + XBF_B + QBF_B + X2_B);
        int*   cand_i = (int*)  (ws + XBF_B + QBF_B + X2_B + CAND_B);
        hipLaunchKernelGGL(prep_q,   dim3(512),           dim3(256), 0, stream, Qf, Qbf);
        hipLaunchKernelGGL(prep_x2,  dim3(NPG),           dim3(256), 0, stream, Xf, Xbf, x2);
        hipLaunchKernelGGL(knn_qreg, dim3(16, NPART),     dim3(256), 0, stream, Xbf, Qbf, x2, cand_s, cand_i);
        hipLaunchKernelGGL(finalize, dim3(B / 4),         dim3(256), 0, stream, Qf, Xf, x2, Y, cand_s, cand_i, out, NPART);
    } else {                                   // round-2/3 proven fallback (~13 MB)
        u16*   Qbf    = (u16*)ws;
        float* x2     = (float*)(ws + 2097152);
        float* cand_s = (float*)(ws + 2497152);
        int*   cand_i = (int*)  (ws + 7740032);
        hipLaunchKernelGGL(prep_q,    dim3(512),      dim3(256), 0, stream, Qf, Qbf);
        hipLaunchKernelGGL(x2_kernel, dim3(N / 4),    dim3(256), 0, stream, Xf, x2, N);
        hipLaunchKernelGGL(knn_conv,  dim3(8, 128),   dim3(256), 0, stream, Xf, Qbf, x2, cand_s, cand_i);
        hipLaunchKernelGGL(finalize,  dim3(B / 4),    dim3(256), 0, stream, Qf, Xf, x2, Y, cand_s, cand_i, out, 128);
    }
}

// Round 5
// 692.720 us; speedup vs baseline: 12.3095x; 1.0098x over previous
//
#include <hip/hip_runtime.h>
#include <math.h>

typedef unsigned int   u32;
typedef unsigned short u16;
typedef short short8 __attribute__((ext_vector_type(8)));   // 8 bf16 = 4 VGPRs
typedef float f32x4  __attribute__((ext_vector_type(4)));

constexpr int B    = 2048;
constexpr int D    = 512;
constexpr int N    = 100000;
constexpr int KTOP = 5;
constexpr int NK   = 16;                  // 512 / 32

// Big path: Q-resident kernel. 16-point groups (pg) are the N-tile unit.
constexpr int NPART    = 64;
constexpr int CHUNK    = 1568;            // 98 pgs of 16; 64*1568 = 100352 >= N
constexpr int PGPART   = CHUNK / 16;      // 98
constexpr int NPTS_PAD = NPART * CHUNK;   // 100352
constexpr int NPG      = NPTS_PAD / 16;   // 6272
constexpr int ITERS    = PGPART / 2;      // 49 double-pg iterations

__device__ __forceinline__ u16 f2bf(float f) {   // RNE, finite normals
    u32 u = __float_as_uint(f);
    return (u16)((u + 0x7fffu + ((u >> 16) & 1u)) >> 16);
}

__device__ __forceinline__ void gld_lds16(const void* g, void* l) {
    __builtin_amdgcn_global_load_lds((const __attribute__((address_space(1))) u32*)g,
                                     (__attribute__((address_space(3))) u32*)l, 16, 0, 0);
}

__device__ __forceinline__ void ins5(float (&s)[KTOP], int (&x)[KTOP], float v, int p) {
    if (v > s[KTOP - 1]) {                 // strict >: earlier (lower) idx wins ties
        s[KTOP - 1] = v; x[KTOP - 1] = p;
#pragma unroll
        for (int k = KTOP - 1; k > 0; --k) {
            if (s[k] > s[k - 1]) {
                float tf = s[k]; s[k] = s[k - 1]; s[k - 1] = tf;
                int   tg = x[k]; x[k] = x[k - 1]; x[k - 1] = tg;
            }
        }
    }
}

__device__ __forceinline__ void merge_xor(float (&s)[KTOP], int (&x)[KTOP], int mask) {
    float bs[KTOP], as[KTOP]; int bx[KTOP], ax[KTOP];
#pragma unroll
    for (int k = 0; k < KTOP; ++k) {
        bs[k] = __shfl_xor(s[k], mask); bx[k] = __shfl_xor(x[k], mask);
        as[k] = s[k]; ax[k] = x[k];
    }
#pragma unroll
    for (int k = 0; k < KTOP; ++k) {
        bool ta = (as[0] > bs[0]) || ((as[0] == bs[0]) && (ax[0] < bx[0]));
        s[k] = ta ? as[0] : bs[0];
        x[k] = ta ? ax[0] : bx[0];
#pragma unroll
        for (int m = 0; m < KTOP - 1; ++m) {
            as[m] = ta ? as[m + 1] : as[m];     ax[m] = ta ? ax[m + 1] : ax[m];
            bs[m] = ta ? bs[m]     : bs[m + 1]; bx[m] = ta ? bx[m]     : bx[m + 1];
        }
        as[KTOP - 1] = ta ? -INFINITY : as[KTOP - 1];
        bs[KTOP - 1] = ta ? bs[KTOP - 1] : -INFINITY;
    }
}

// ---- Q -> bf16 in MFMA B-frag order (verified rounds 2-4) -----------------
__global__ void prep_q(const float* __restrict__ Q, u16* __restrict__ Qbf) {
    int tid  = blockIdx.x * 256 + threadIdx.x;     // 131072
    int q    = tid >> 6;
    int koct = tid & 63;
    const float4* src = (const float4*)(Q + (size_t)q * D + koct * 8);
    float4 a = src[0], b = src[1];
    u32 p0 = (u32)f2bf(a.x) | ((u32)f2bf(a.y) << 16);
    u32 p1 = (u32)f2bf(a.z) | ((u32)f2bf(a.w) << 16);
    u32 p2 = (u32)f2bf(b.x) | ((u32)f2bf(b.y) << 16);
    u32 p3 = (u32)f2bf(b.z) | ((u32)f2bf(b.w) << 16);
    int frag = (q >> 4) * NK + (koct >> 2);
    int lane = (q & 15) + 16 * (koct & 3);
    *(uint4*)(Qbf + (size_t)frag * 512 + lane * 8) = make_uint4(p0, p1, p2, p3);
}

// ---- X -> bf16 A-frags (layout verified rounds 3/4) + fused x2 ------------
__global__ void prep_x2(const float* __restrict__ X, u16* __restrict__ Xbf,
                        float* __restrict__ x2) {
    __shared__ float psum[4][16];
    const int t = threadIdx.x, lane = t & 63, wave = t >> 6;
    const int pg    = blockIdx.x;                 // 0..NPG-1
    const int point = pg * 16 + (lane & 15);
    float ssum = 0.f;
#pragma unroll
    for (int u = 0; u < 4; ++u) {
        int k0i = wave * 4 + u;
        int k   = k0i * 32 + ((lane >> 4) << 3);
        uint4 o = make_uint4(0u, 0u, 0u, 0u);
        if (point < N) {
            const float4* src = (const float4*)(X + (size_t)point * D + k);
            float4 a = src[0], b = src[1];
            ssum = fmaf(a.x, a.x, ssum); ssum = fmaf(a.y, a.y, ssum);
            ssum = fmaf(a.z, a.z, ssum); ssum = fmaf(a.w, a.w, ssum);
            ssum = fmaf(b.x, b.x, ssum); ssum = fmaf(b.y, b.y, ssum);
            ssum = fmaf(b.z, b.z, ssum); ssum = fmaf(b.w, b.w, ssum);
            o.x = (u32)f2bf(a.x) | ((u32)f2bf(a.y) << 16);
            o.y = (u32)f2bf(a.z) | ((u32)f2bf(a.w) << 16);
            o.z = (u32)f2bf(b.x) | ((u32)f2bf(b.y) << 16);
            o.w = (u32)f2bf(b.z) | ((u32)f2bf(b.w) << 16);
        }
        *(uint4*)(Xbf + ((size_t)pg * 16 + k0i) * 512 + lane * 8) = o;
    }
    ssum += __shfl_xor(ssum, 16);
    ssum += __shfl_xor(ssum, 32);
    if (lane < 16) psum[wave][lane] = ssum;
    __syncthreads();
    if (t < 16) {
        float s = psum[0][t] + psum[1][t] + psum[2][t] + psum[3][t];
        x2[pg * 16 + t] = (pg * 16 + t < N) ? s : INFINITY;
    }
}

// ---- x2 (fallback path only) ----------------------------------------------
__global__ void x2_kernel(const float* __restrict__ X, float* __restrict__ x2, int total) {
    int lane = threadIdx.x & 63;
    int wid  = (int)((blockIdx.x * blockDim.x + threadIdx.x) >> 6);
    if (wid >= total) return;
    if (wid >= N) { if (lane == 0) x2[wid] = INFINITY; return; }
    const float* row = X + (size_t)wid * D;
    float s = 0.f;
    for (int c = lane; c < D; c += 64) { float v = row[c]; s = fmaf(v, v, s); }
#pragma unroll
    for (int off = 32; off > 0; off >>= 1) s += __shfl_down(s, off);
    if (lane == 0) x2[wid] = s;
}

// ---- main: Q resident in registers; X streams through LDS, 2 pgs/barrier --
__launch_bounds__(256, 2)
__global__ void knn_qreg(const u16* __restrict__ Xbf, const u16* __restrict__ Qbf,
                         const float* __restrict__ x2g,
                         float* __restrict__ cand_s, int* __restrict__ cand_i) {
    __shared__ __attribute__((aligned(16))) u16 Afr[2][32 * 512];   // 2 x 32KB (2 pgs each)
    const int t    = threadIdx.x;
    const int lane = t & 63;
    const int wave = t >> 6;
    const int quad = lane >> 4;
    const int col  = lane & 15;
    const int part = blockIdx.x;          // 0..63  (x-fastest: 16 qb blocks of a
    const int qb   = blockIdx.y;          // 0..15   part land on one XCD, %8 rr)
    const int pg0    = part * PGPART;
    const int pstart = part * CHUNK;

    // Resident Q: 2 query-groups x 16 k-steps = 128 VGPRs
    short8 bq[2][16];
#pragma unroll
    for (int j = 0; j < 2; ++j) {
        int qg = qb * 8 + wave * 2 + j;
#pragma unroll
        for (int k0i = 0; k0i < 16; ++k0i)
            bq[j][k0i] = *(const short8*)(Qbf + ((size_t)qg * 16 + k0i) * 512 + lane * 8);
    }
    // Pin bq in registers: memory clobber forbids re-loading from Qbf in-loop.
    asm volatile("" ::: "memory");

    float ss[2][KTOP]; int si[2][KTOP];
#pragma unroll
    for (int j = 0; j < 2; ++j)
#pragma unroll
        for (int k = 0; k < KTOP; ++k) { ss[j][k] = -INFINITY; si[j][k] = 0x7fffffff; }

    auto issue = [&](int it, int bsel) {      // stage pgs 2*it, 2*it+1
        const size_t pgA = (size_t)(pg0 + 2 * it);
        const u16* srcA = Xbf + (pgA * 16 + wave * 4) * 512 + (lane << 3);
        u16* dstA = Afr[bsel] + (wave * 4) * 512;          // wave-uniform LDS base
        u16* dstB = dstA + 16 * 512;
#pragma unroll
        for (int f = 0; f < 4; ++f) {
            gld_lds16(srcA + f * 512, dstA + f * 512);
            gld_lds16(srcA + (16 + f) * 512, dstB + f * 512);  // pgB = pgA+1
        }
    };

    issue(0, 0);
    for (int it = 0; it < ITERS; ++it) {
        const int bsel = it & 1;
        __syncthreads();                               // drains prior-iter gld_lds
        if (it + 1 < ITERS) issue(it + 1, bsel ^ 1);
        const int PA = pstart + (2 * it) * 16;
        const int PB = PA + 16;
        float4 xxA = *(const float4*)(x2g + PA + quad * 4);
        float4 xxB = *(const float4*)(x2g + PB + quad * 4);

        f32x4 accA0 = (f32x4)0.f, accA1 = (f32x4)0.f;
        f32x4 accB0 = (f32x4)0.f, accB1 = (f32x4)0.f;
#pragma unroll
        for (int k0i = 0; k0i < 16; ++k0i) {
            short8 afA = *(const short8*)&Afr[bsel][k0i * 512 + lane * 8];
            short8 afB = *(const short8*)&Afr[bsel][(16 + k0i) * 512 + lane * 8];
            accA0 = __builtin_amdgcn_mfma_f32_16x16x32_bf16(afA, bq[0][k0i], accA0, 0, 0, 0);
            accA1 = __builtin_amdgcn_mfma_f32_16x16x32_bf16(afA, bq[1][k0i], accA1, 0, 0, 0);
            accB0 = __builtin_amdgcn_mfma_f32_16x16x32_bf16(afB, bq[0][k0i], accB0, 0, 0, 0);
            accB1 = __builtin_amdgcn_mfma_f32_16x16x32_bf16(afB, bq[1][k0i], accB1, 0, 0, 0);
        }
        // C layout: col=lane&15 (query), row=quad*4+reg (point)
        {
            const int gbase = PA + quad * 4;
            float s0 = fmaf(2.f, accA0[0], -xxA.x);
            float s1 = fmaf(2.f, accA0[1], -xxA.y);
            float s2 = fmaf(2.f, accA0[2], -xxA.z);
            float s3 = fmaf(2.f, accA0[3], -xxA.w);
            float mx = fmaxf(fmaxf(s0, s1), fmaxf(s2, s3));
            if (mx > ss[0][KTOP - 1]) {
                ins5(ss[0], si[0], s0, gbase + 0); ins5(ss[0], si[0], s1, gbase + 1);
                ins5(ss[0], si[0], s2, gbase + 2); ins5(ss[0], si[0], s3, gbase + 3);
            }
            s0 = fmaf(2.f, accA1[0], -xxA.x);
            s1 = fmaf(2.f, accA1[1], -xxA.y);
            s2 = fmaf(2.f, accA1[2], -xxA.z);
            s3 = fmaf(2.f, accA1[3], -xxA.w);
            mx = fmaxf(fmaxf(s0, s1), fmaxf(s2, s3));
            if (mx > ss[1][KTOP - 1]) {
                ins5(ss[1], si[1], s0, gbase + 0); ins5(ss[1], si[1], s1, gbase + 1);
                ins5(ss[1], si[1], s2, gbase + 2); ins5(ss[1], si[1], s3, gbase + 3);
            }
        }
        {
            const int gbase = PB + quad * 4;
            float s0 = fmaf(2.f, accB0[0], -xxB.x);
            float s1 = fmaf(2.f, accB0[1], -xxB.y);
            float s2 = fmaf(2.f, accB0[2], -xxB.z);
            float s3 = fmaf(2.f, accB0[3], -xxB.w);
            float mx = fmaxf(fmaxf(s0, s1), fmaxf(s2, s3));
            if (mx > ss[0][KTOP - 1]) {
                ins5(ss[0], si[0], s0, gbase + 0); ins5(ss[0], si[0], s1, gbase + 1);
                ins5(ss[0], si[0], s2, gbase + 2); ins5(ss[0], si[0], s3, gbase + 3);
            }
            s0 = fmaf(2.f, accB1[0], -xxB.x);
            s1 = fmaf(2.f, accB1[1], -xxB.y);
            s2 = fmaf(2.f, accB1[2], -xxB.z);
            s3 = fmaf(2.f, accB1[3], -xxB.w);
            mx = fmaxf(fmaxf(s0, s1), fmaxf(s2, s3));
            if (mx > ss[1][KTOP - 1]) {
                ins5(ss[1], si[1], s0, gbase + 0); ins5(ss[1], si[1], s1, gbase + 1);
                ins5(ss[1], si[1], s2, gbase + 2); ins5(ss[1], si[1], s3, gbase + 3);
            }
        }
    }

#pragma unroll
    for (int j = 0; j < 2; ++j) { merge_xor(ss[j], si[j], 16); merge_xor(ss[j], si[j], 32); }
    if (quad == 0) {
#pragma unroll
        for (int j = 0; j < 2; ++j) {
            int q = qb * 128 + wave * 32 + j * 16 + col;
            size_t base = ((size_t)q * NPART + part) * KTOP;
#pragma unroll
            for (int k = 0; k < KTOP; ++k) { cand_s[base + k] = ss[j][k]; cand_i[base + k] = si[j][k]; }
        }
    }
}

// ---- fallback main (round-2/3 proven path, in-loop conversion) ------------
__launch_bounds__(256)
__global__ void knn_conv(const float* __restrict__ X, const u16* __restrict__ Qbf,
                         const float* __restrict__ x2g,
                         float* __restrict__ cand_s, int* __restrict__ cand_i) {
    __shared__ __attribute__((aligned(16))) u16 Bfr[16 * 512];
    __shared__ __attribute__((aligned(16))) u16 Afr[4 * 512];
    __shared__ float x2s[64];
    const int t = threadIdx.x, lane = t & 63, wave = t >> 6;
    const int quad = lane >> 4, col = lane & 15;
    const int qb = blockIdx.x, part = blockIdx.y;
    const int pstart = part * 782;
    const int pend   = min(pstart + 782, N);

    float ss[4][KTOP]; int si[4][KTOP];
#pragma unroll
    for (int j = 0; j < 4; ++j)
#pragma unroll
        for (int k = 0; k < KTOP; ++k) { ss[j][k] = -INFINITY; si[j][k] = 0x7fffffff; }

    const int nsub = (pend - pstart + 63) / 64;
    for (int sbi = 0; sbi < nsub; ++sbi) {
        const int sb = pstart + sbi * 64;
        __syncthreads();
        if (t < 64) x2s[t] = (sb + t < pend) ? x2g[sb + t] : INFINITY;
        f32x4 acc[4][4];
#pragma unroll
        for (int i = 0; i < 4; ++i)
#pragma unroll
            for (int j = 0; j < 4; ++j) acc[i][j] = (f32x4)0.f;
        for (int k0i = 0; k0i < NK; ++k0i) {
            const int k0 = k0i * 32;
            __syncthreads();
            {
                int prow = sb + wave * 16 + col;
                if (prow >= pend) prow = pend - 1;
                const float4* src = (const float4*)(X + (size_t)prow * D + k0 + quad * 8);
                float4 a = src[0], b = src[1];
                u32 p0 = (u32)f2bf(a.x) | ((u32)f2bf(a.y) << 16);
                u32 p1 = (u32)f2bf(a.z) | ((u32)f2bf(a.w) << 16);
                u32 p2 = (u32)f2bf(b.x) | ((u32)f2bf(b.y) << 16);
                u32 p3 = (u32)f2bf(b.z) | ((u32)f2bf(b.w) << 16);
                *(uint4*)(Afr + wave * 512 + lane * 8) = make_uint4(p0, p1, p2, p3);
            }
#pragma unroll
            for (int j = 0; j < 4; ++j) {
                int qgrp = qb * 16 + wave * 4 + j;
                gld_lds16(Qbf + ((size_t)qgrp * NK + k0i) * 512 + lane * 8,
                          (void*)(Bfr + (wave * 4 + j) * 512));
            }
            __syncthreads();
            short8 af[4], bqf[4];
#pragma unroll
            for (int i = 0; i < 4; ++i) af[i] = *(const short8*)(Afr + i * 512 + lane * 8);
#pragma unroll
            for (int j = 0; j < 4; ++j) bqf[j] = *(const short8*)(Bfr + (wave * 4 + j) * 512 + lane * 8);
#pragma unroll
            for (int i = 0; i < 4; ++i)
#pragma unroll
                for (int j = 0; j < 4; ++j)
                    acc[i][j] = __builtin_amdgcn_mfma_f32_16x16x32_bf16(af[i], bqf[j], acc[i][j], 0, 0, 0);
        }
#pragma unroll
        for (int i = 0; i < 4; ++i) {
            int pb = 16 * i + quad * 4;
#pragma unroll
            for (int j = 0; j < 4; ++j)
#pragma unroll
                for (int r = 0; r < 4; ++r)
                    ins5(ss[j], si[j], 2.f * acc[i][j][r] - x2s[pb + r], sb + pb + r);
        }
    }
#pragma unroll
    for (int j = 0; j < 4; ++j) { merge_xor(ss[j], si[j], 16); merge_xor(ss[j], si[j], 32); }
    if (quad == 0) {
#pragma unroll
        for (int j = 0; j < 4; ++j) {
            int qg = qb * 256 + wave * 64 + j * 16 + col;
            size_t base = ((size_t)qg * 128 + part) * KTOP;
#pragma unroll
            for (int k = 0; k < KTOP; ++k) { cand_s[base + k] = ss[j][k]; cand_i[base + k] = si[j][k]; }
        }
    }
}

// ---- finalize: pool npart*5 cands -> approx top-16 -> exact rescore -> vote
__launch_bounds__(256)
__global__ void finalize(const float* __restrict__ Q, const float* __restrict__ X,
                         const float* __restrict__ x2g, const int* __restrict__ Y,
                         const float* __restrict__ cand_s, const int* __restrict__ cand_i,
                         float* __restrict__ out, int npart) {
    __shared__ float scs[4][96];
    __shared__ int   sis[4][96];
    const int t = threadIdx.x, lane = t & 63, w = t >> 6;
    const int q = blockIdx.x * 4 + w;
    const int perlane = npart * KTOP / 16;

    if (lane < 16) {
        float ls[KTOP]; int li[KTOP];
#pragma unroll
        for (int k = 0; k < KTOP; ++k) { ls[k] = -INFINITY; li[k] = 0x7fffffff; }
        const float* cs = cand_s + (size_t)q * npart * KTOP + lane * perlane;
        const int*   ci = cand_i + (size_t)q * npart * KTOP + lane * perlane;
        for (int c = 0; c < perlane; ++c) {
            float s = cs[c]; int p = ci[c];
            if (s > ls[KTOP - 1] || (s == ls[KTOP - 1] && p < li[KTOP - 1])) {
                ls[KTOP - 1] = s; li[KTOP - 1] = p;
#pragma unroll
                for (int k = KTOP - 1; k > 0; --k) {
                    bool up = (ls[k] > ls[k - 1]) || (ls[k] == ls[k - 1] && li[k] < li[k - 1]);
                    if (up) {
                        float tf = ls[k]; ls[k] = ls[k - 1]; ls[k - 1] = tf;
                        int   tg = li[k]; li[k] = li[k - 1]; li[k - 1] = tg;
                    }
                }
            }
        }
#pragma unroll
        for (int k = 0; k < KTOP; ++k) { scs[w][lane * KTOP + k] = ls[k]; sis[w][lane * KTOP + k] = li[k]; }
    }
    __syncthreads();
    if (lane == 0) {
        float bs[16]; int bx[16];
#pragma unroll
        for (int m = 0; m < 16; ++m) { bs[m] = -INFINITY; bx[m] = 0x7fffffff; }
        for (int c = 0; c < 80; ++c) {
            float s = scs[w][c]; int p = sis[w][c];
            if (s > bs[15] || (s == bs[15] && p < bx[15])) {
                bs[15] = s; bx[15] = p;
#pragma unroll
                for (int m = 15; m > 0; --m) {
                    bool up = (bs[m] > bs[m - 1]) || (bs[m] == bs[m - 1] && bx[m] < bx[m - 1]);
                    if (up) {
                        float tf = bs[m]; bs[m] = bs[m - 1]; bs[m - 1] = tf;
                        int   tg = bx[m]; bx[m] = bx[m - 1]; bx[m - 1] = tg;
                    }
                }
            }
        }
#pragma unroll
        for (int m = 0; m < 16; ++m) sis[w][80 + m] = bx[m];
    }
    __syncthreads();
    const int c = lane & 15, seg = lane >> 4;
    int idx = sis[w][80 + c];
    const float4* xr = (const float4*)(X + (size_t)idx * D);
    const float4* qr = (const float4*)(Q + (size_t)q * D);
    float d = 0.f;
    for (int u = seg * 32; u < seg * 32 + 32; ++u) {
        float4 a = qr[u], b = xr[u];
        d = fmaf(a.x, b.x, d); d = fmaf(a.y, b.y, d);
        d = fmaf(a.z, b.z, d); d = fmaf(a.w, b.w, d);
    }
    d += __shfl_xor(d, 16);
    d += __shfl_xor(d, 32);
    float sc = 2.f * d - x2g[idx];
    if (seg == 0) scs[w][80 + c] = sc;
    __syncthreads();
    if (lane == 0) {
        float bs[KTOP]; int bx[KTOP];
#pragma unroll
        for (int k = 0; k < KTOP; ++k) { bs[k] = -INFINITY; bx[k] = 0x7fffffff; }
        for (int c2 = 0; c2 < 16; ++c2) {
            float s = scs[w][80 + c2]; int p = sis[w][80 + c2];
            if (s > bs[KTOP - 1] || (s == bs[KTOP - 1] && p < bx[KTOP - 1])) {
                bs[KTOP - 1] = s; bx[KTOP - 1] = p;
#pragma unroll
                for (int k = KTOP - 1; k > 0; --k) {
                    bool up = (bs[k] > bs[k - 1]) || (bs[k] == bs[k - 1] && bx[k] < bx[k - 1]);
                    if (up) {
                        float tf = bs[k]; bs[k] = bs[k - 1]; bs[k - 1] = tf;
                        int   tg = bx[k]; bx[k] = bx[k - 1]; bx[k - 1] = tg;
                    }
                }
            }
        }
        float sum = 0.f;
#pragma unroll
        for (int k = 0; k < KTOP; ++k) sum += (float)Y[bx[k]];
        out[2 * q]     = sum * 0.2f;
        out[2 * q + 1] = 0.f;
    }
}

extern "C" void kernel_launch(void* const* d_in, const int* in_sizes, int n_in,
                              void* d_out, int out_size, void* d_ws, size_t ws_size,
                              hipStream_t stream) {
    const float* Qf = (const float*)d_in[0];
    const float* Xf = (const float*)d_in[1];
    const int*   Y  = (const int*)d_in[2];
    float* out = (float*)d_out;
    char* ws = (char*)d_ws;

    constexpr size_t XBF_B  = (size_t)NPG * NK * 1024;        // 102,760,448
    constexpr size_t QBF_B  = 2097152;
    constexpr size_t X2_B   = (size_t)NPTS_PAD * 4;           //     401,408
    constexpr size_t CAND_B = (size_t)B * NPART * KTOP * 4;   //   2,621,440
    constexpr size_t NEED   = XBF_B + QBF_B + X2_B + 2 * CAND_B;

    if (ws_size >= NEED) {
        u16*   Xbf    = (u16*)ws;
        u16*   Qbf    = (u16*)(ws + XBF_B);
        float* x2     = (float*)(ws + XBF_B + QBF_B);
        float* cand_s = (float*)(ws + XBF_B + QBF_B + X2_B);
        int*   cand_i = (int*)  (ws + XBF_B + QBF_B + X2_B + CAND_B);
        hipLaunchKernelGGL(prep_q,   dim3(512),       dim3(256), 0, stream, Qf, Qbf);
        hipLaunchKernelGGL(prep_x2,  dim3(NPG),       dim3(256), 0, stream, Xf, Xbf, x2);
        hipLaunchKernelGGL(knn_qreg, dim3(NPART, 16), dim3(256), 0, stream, Xbf, Qbf, x2, cand_s, cand_i);
        hipLaunchKernelGGL(finalize, dim3(B / 4),     dim3(256), 0, stream, Qf, Xf, x2, Y, cand_s, cand_i, out, NPART);
    } else {                                   // round-2/3 proven fallback (~13 MB)
        u16*   Qbf    = (u16*)ws;
        float* x2     = (float*)(ws + 2097152);
        float* cand_s = (float*)(ws + 2497152);
        int*   cand_i = (int*)  (ws + 7740032);
        hipLaunchKernelGGL(prep_q,    dim3(512),      dim3(256), 0, stream, Qf, Qbf);
        hipLaunchKernelGGL(x2_kernel, dim3(N / 4),    dim3(256), 0, stream, Xf, x2, N);
        hipLaunchKernelGGL(knn_conv,  dim3(8, 128),   dim3(256), 0, stream, Xf, Qbf, x2, cand_s, cand_i);
        hipLaunchKernelGGL(finalize,  dim3(B / 4),    dim3(256), 0, stream, Qf, Xf, x2, Y, cand_s, cand_i, out, 128);
    }
}